// Round 1
// 314.428 us; speedup vs baseline: 1.0622x; 1.0622x over previous
//
#include <hip/hip_runtime.h>

// Upsample 2x depthwise transposed conv, FIR k1=[1,3,3,1], factor=2 (separable).
// out[2i]   = (x[i-1] + 3*x[i]) / 4
// out[2i+1] = (3*x[i] + x[i+1]) / 4   (zero padding at edges)
// Input (8,128,128,128) fp32 -> Output (8,128,256,256) fp32
//
// Wave-persistent rolling-row design:
//  - 64-lane wave covers one full 128-px input row at 2 px/lane (float2 loads).
//  - Each wave walks a 16-row strip of one image, rolling a/b/c row registers
//    so each input row is loaded once (plus 2 halo rows per strip: 1.125x).
//  - Each lane stores one float4 per output row: a store instruction is
//    64 lanes x 16 B = 1 KB fully contiguous = exactly one output row.
//  - Grid 1024 blocks x 512 threads = 8192 waves = 32 waves/CU (full occupancy).

#define IN_H 128
#define IN_W 128
#define ROWS_PER_WAVE 16   // 8 waves/block * 16 rows = 128 rows = one image

__global__ __launch_bounds__(512) void upsample_fir_kernel(
    const float* __restrict__ x, float* __restrict__ out) {
    const int lane = threadIdx.x & 63;
    const int wv   = threadIdx.x >> 6;        // 0..7: strip within image
    const int bc   = blockIdx.x;              // 0..1023: batch*channel
    const int iy0  = wv * ROWS_PER_WAVE;

    const float* xp = x + (size_t)bc * (IN_H * IN_W);
    const int OW = 2 * IN_W;
    float* op = out + (size_t)bc * (2 * IN_H) * OW + 4 * lane;

    const float2 z2 = make_float2(0.f, 0.f);

    // rolling window: a = row iy-1, b = row iy, c = row iy+1
    float2 a = (iy0 > 0) ? ((const float2*)(xp + (iy0 - 1) * IN_W))[lane] : z2;
    float2 b = ((const float2*)(xp + iy0 * IN_W))[lane];

    #pragma unroll 4
    for (int iy = iy0; iy < iy0 + ROWS_PER_WAVE; ++iy) {
        // unconditional load from clamped row (row 127 re-read then masked);
        // keeps the load unpredicated so the compiler can hoist it early.
        const int ny = (iy + 1 < IN_H) ? (iy + 1) : (IN_H - 1);
        float2 cr = ((const float2*)(xp + ny * IN_W))[lane];
        float2 c;
        c.x = (iy + 1 < IN_H) ? cr.x : 0.f;
        c.y = (iy + 1 < IN_H) ? cr.y : 0.f;

        // vertical pass: t -> output row 2*iy, u -> output row 2*iy+1
        float2 t, u;
        t.x = (a.x + 3.f * b.x) * 0.25f;  u.x = (3.f * b.x + c.x) * 0.25f;
        t.y = (a.y + 3.f * b.y) * 0.25f;  u.y = (3.f * b.y + c.y) * 0.25f;

        // horizontal neighbors via wave shuffle (64-lane wave == image row)
        float t_l = __shfl_up(t.y, 1);   if (lane == 0)  t_l = 0.f;
        float t_r = __shfl_down(t.x, 1); if (lane == 63) t_r = 0.f;
        float u_l = __shfl_up(u.y, 1);   if (lane == 0)  u_l = 0.f;
        float u_r = __shfl_down(u.x, 1); if (lane == 63) u_r = 0.f;

        // horizontal pass: lane emits out px [4*lane .. 4*lane+3] of each row
        float4 o, p;
        o.x = (t_l + 3.f * t.x) * 0.25f;
        o.y = (3.f * t.x + t.y) * 0.25f;
        o.z = (t.x + 3.f * t.y) * 0.25f;
        o.w = (3.f * t.y + t_r) * 0.25f;
        p.x = (u_l + 3.f * u.x) * 0.25f;
        p.y = (3.f * u.x + u.y) * 0.25f;
        p.z = (u.x + 3.f * u.y) * 0.25f;
        p.w = (3.f * u.y + u_r) * 0.25f;

        float* ob = op + (size_t)(2 * iy) * OW;
        *(float4*)(ob)      = o;   // one full 1 KB output row per instruction
        *(float4*)(ob + OW) = p;

        a = b; b = c;
    }
}

extern "C" void kernel_launch(void* const* d_in, const int* in_sizes, int n_in,
                              void* d_out, int out_size, void* d_ws, size_t ws_size,
                              hipStream_t stream) {
    const float* x = (const float*)d_in[0];
    float* out = (float*)d_out;
    // 1024 images (B*C), one block each; 8 waves/block, 16-row strip per wave
    upsample_fir_kernel<<<8 * 128, 512, 0, stream>>>(x, out);
}

// Round 2
// 307.305 us; speedup vs baseline: 1.0868x; 1.0232x over previous
//
#include <hip/hip_runtime.h>

// Upsample 2x depthwise transposed conv, FIR k1=[1,3,3,1], factor=2 (separable).
// out[2i]   = (x[i-1] + 3*x[i]) / 4
// out[2i+1] = (3*x[i] + x[i+1]) / 4   (zero padding at edges)
// Input (8,128,128,128) fp32 -> Output (8,128,256,256) fp32
//
// v3: strip-resident register design, max MLP.
//  - 64-lane wave = one full 128-px input row at 2 px/lane (float2).
//  - Each wave owns an 8-row strip; ALL 10 row-loads (8 + 2 halo) are issued
//    up-front into a statically-indexed register array, so 10 loads are in
//    flight per wave and the fully-unrolled compute drains them with
//    descending vmcnt waits (no per-iteration load->compute serialization).
//  - Vertical pass folded to one FMA/elem (t = a + 3b, scale deferred);
//    single *1/16 at the end.
//  - Each lane stores one float4 per output row: one store instruction
//    = 64 lanes x 16 B = 1 KB = exactly one output row (fully dense).
//  - 4096 blocks x 256 thr = 16384 waves = 2 uniform occupancy rounds at
//    8 waves/SIMD (low VGPR), no partial tail.

#define IN_H 128
#define IN_W 128
#define ROWS 8   // input rows per wave strip

__global__ __launch_bounds__(256) void upsample_fir_kernel(
    const float* __restrict__ x, float* __restrict__ out) {
    const int lane  = threadIdx.x & 63;
    const int wv    = threadIdx.x >> 6;           // 0..3
    const int strip = blockIdx.x * 4 + wv;        // 0..16383
    const int bc    = strip >> 4;                 // image index (16 strips/img)
    const int iy0   = (strip & 15) * ROWS;        // first input row of strip

    const float2* xr = (const float2*)(x + (size_t)bc * (IN_H * IN_W)) + lane;
    // input row i of this image = xr[i * 64]

    const float2 z2 = make_float2(0.f, 0.f);
    float2 r[ROWS + 2];                           // rows iy0-1 .. iy0+ROWS

    // issue all strip loads up-front (10 loads in flight)
    r[0] = (iy0 > 0) ? xr[(iy0 - 1) * (IN_W / 2)] : z2;
    #pragma unroll
    for (int k = 0; k < ROWS + 1; ++k) {
        const int ry = iy0 + k;                   // valid except possibly last
        r[k + 1] = (ry < IN_H) ? xr[ry * (IN_W / 2)] : z2;
    }

    const int OW = 2 * IN_W;
    float* ob = out + (size_t)bc * (2 * IN_H) * OW + (size_t)(2 * iy0) * OW
              + 4 * lane;

    const float s16 = 1.f / 16.f;

    #pragma unroll
    for (int k = 0; k < ROWS; ++k) {
        const float2 A = r[k], B = r[k + 1], C = r[k + 2];

        // vertical pass (unscaled): t -> out row 2*(iy0+k), u -> +1
        float2 t, u;
        t.x = fmaf(3.f, B.x, A.x);  t.y = fmaf(3.f, B.y, A.y);
        u.x = fmaf(3.f, B.x, C.x);  u.y = fmaf(3.f, B.y, C.y);

        // horizontal neighbors via wave shuffle (64-lane wave == image row)
        float t_l = __shfl_up(t.y, 1);   if (lane == 0)  t_l = 0.f;
        float t_r = __shfl_down(t.x, 1); if (lane == 63) t_r = 0.f;
        float u_l = __shfl_up(u.y, 1);   if (lane == 0)  u_l = 0.f;
        float u_r = __shfl_down(u.x, 1); if (lane == 63) u_r = 0.f;

        // horizontal pass, single *1/16: lane emits out px [4L .. 4L+3]
        float4 o, p;
        o.x = fmaf(3.f, t.x, t_l) * s16;
        o.y = fmaf(3.f, t.x, t.y) * s16;
        o.z = fmaf(3.f, t.y, t.x) * s16;
        o.w = fmaf(3.f, t.y, t_r) * s16;
        p.x = fmaf(3.f, u.x, u_l) * s16;
        p.y = fmaf(3.f, u.x, u.y) * s16;
        p.z = fmaf(3.f, u.y, u.x) * s16;
        p.w = fmaf(3.f, u.y, u_r) * s16;

        float* orow = ob + (size_t)(2 * k) * OW;
        *(float4*)(orow)      = o;   // 1 KB dense store = one output row
        *(float4*)(orow + OW) = p;
    }
}

extern "C" void kernel_launch(void* const* d_in, const int* in_sizes, int n_in,
                              void* d_out, int out_size, void* d_ws, size_t ws_size,
                              hipStream_t stream) {
    const float* x = (const float*)d_in[0];
    float* out = (float*)d_out;
    // 1024 images * 16 strips = 16384 waves; 4 waves (256 thr) per block
    upsample_fir_kernel<<<4096, 256, 0, stream>>>(x, out);
}